// Round 6
// baseline (268.499 us; speedup 1.0000x reference)
//
#include <hip/hip_runtime.h>
#include <hip/hip_bf16.h>

#define B_ 2
#define P_ 100000
#define CIN_ 23
#define C_ 64
#define H_ 512
#define W_ 512
#define S_ (H_*W_)       // 262144
#define NPT_ (B_*P_)     // 200000
#define NVOX_ (B_*S_)    // 524288

typedef __attribute__((ext_vector_type(8))) short short8;
typedef __attribute__((ext_vector_type(4))) float f32x4;

__device__ inline unsigned short f2bf(float f) {
    union { __hip_bfloat16 h; unsigned short u; } cv;
    cv.h = __float2bfloat16(f);
    return cv.u;
}
__device__ inline float bf2f(unsigned short u) {
    union { unsigned int i; float f; } cv;
    cv.i = ((unsigned int)u) << 16;
    return cv.f;
}

// ---------------- Stage 1: lists + compact occupied-voxel worklist ----------------
__global__ __launch_bounds__(256) void k_fill(
    const int* __restrict__ indices,
    const int* __restrict__ paddings,
    int* __restrict__ head,
    int* __restrict__ next,
    int* __restrict__ wl,
    int* __restrict__ cnt)
{
    int pt = blockIdx.x * 256 + threadIdx.x;
    if (pt >= NPT_) return;
    if (paddings[pt] != 0) return;              // padded -> dropped
    int v = (pt / P_) * S_ + indices[pt];
    int old = atomicExch(&head[v], pt);
    next[pt] = old;
    if (old < 0) {                              // first toucher appends voxel
        int slot = atomicAdd(cnt, 1);
        wl[slot] = v;
    }
}

// ---------------- Stage 2: FUSED PointNet-max + BN1 + 1x1conv + BN2 + ReLU ----------
// one wave per 16 occupied voxels: 16 concurrent chain walks -> LDS transpose
// (XOR-swizzled) -> MFMA 16x16x32 conv -> final bf16 rows
__global__ __launch_bounds__(256) void k_pn_conv(
    const float* __restrict__ feat,
    const int* __restrict__ head,
    const int* __restrict__ next,
    const int* __restrict__ wl,
    const float* __restrict__ w_pn,
    const float* __restrict__ g1, const float* __restrict__ b1,
    const float* __restrict__ m1, const float* __restrict__ v1,
    const float* __restrict__ conv_w,       // [out n][in k] f32
    const float* __restrict__ g2, const float* __restrict__ b2,
    const float* __restrict__ m2, const float* __restrict__ v2,
    unsigned short* __restrict__ grid)      // bf16 [NVOX_][C_] (final values)
{
    __shared__ unsigned short lds[4][16][64];   // per-wave 16x64 bf16 tile, 8KB

    // block-uniform early out: wl tail of -1s is contiguous
    if (wl[blockIdx.x * 64] < 0) return;

    int tid  = threadIdx.x;
    int wv   = tid >> 6;
    int lane = tid & 63;
    int e0   = blockIdx.x * 64 + wv * 16;       // max 199984+15 < 200000

    bool active = (wl[e0] >= 0);

    // ---- phase 1: 16-chain PointNet walk ----
    int   vx[16], pc[16];
    float mx[16];
    #pragma unroll
    for (int i = 0; i < 16; ++i) {
        vx[i] = active ? wl[e0 + i] : -1;
        pc[i] = vx[i] >= 0 ? head[vx[i]] : -1;
        mx[i] = -1e30f;
    }

    float w[CIN_];
    #pragma unroll
    for (int i = 0; i < CIN_; ++i) w[i] = w_pn[i * C_ + lane];

    bool any = false;
    #pragma unroll
    for (int i = 0; i < 16; ++i) any |= (pc[i] >= 0);
    while (any) {
        #pragma unroll
        for (int i = 0; i < 16; ++i) {
            const float* f = feat + (size_t)(pc[i] < 0 ? 0 : pc[i]) * CIN_;
            int nx = pc[i] < 0 ? -1 : next[pc[i]];
            float acc = 0.f;
            #pragma unroll
            for (int j = 0; j < CIN_; ++j) acc += f[j] * w[j];
            if (pc[i] >= 0) mx[i] = fmaxf(mx[i], acc);
            pc[i] = pc[i] < 0 ? -1 : nx;
        }
        any = false;
        #pragma unroll
        for (int i = 0; i < 16; ++i) any |= (pc[i] >= 0);
    }

    // ---- BN1 + ReLU, write swizzled LDS tile (lane = channel) ----
    float s1   = g1[lane] * rsqrtf(v1[lane] + 1e-5f);
    float off1 = b1[lane] - m1[lane] * s1;
    #pragma unroll
    for (int i = 0; i < 16; ++i) {
        float val = vx[i] >= 0 ? fmaxf(mx[i] * s1 + off1, 0.f) : 0.f;
        lds[wv][i][lane ^ ((i & 7) << 3)] = f2bf(val);
    }

    __syncthreads();
    if (!active) return;

    // ---- phase 2: 1x1 conv via MFMA ----
    int row = lane & 15;
    int grp = lane >> 4;

    short8 bfrag[4][2];
    #pragma unroll
    for (int t = 0; t < 4; ++t)
        #pragma unroll
        for (int ks = 0; ks < 2; ++ks) {
            const float* wp = conv_w + (t * 16 + row) * 64 + ks * 32 + grp * 8;
            f32x4 lo = *(const f32x4*)(wp);
            f32x4 hi = *(const f32x4*)(wp + 4);
            short8 vv;
            #pragma unroll
            for (int j = 0; j < 4; ++j) {
                vv[j]     = (short)f2bf(lo[j]);
                vv[j + 4] = (short)f2bf(hi[j]);
            }
            bfrag[t][ks] = vv;
        }

    float sc[4], sh[4];
    #pragma unroll
    for (int t = 0; t < 4; ++t) {
        int n   = t * 16 + row;
        float s = g2[n] * rsqrtf(v2[n] + 1e-3f);
        sc[t] = s;
        sh[t] = b2[n] - m2[n] * s;
    }

    // A fragments from swizzled LDS: row r, channels (ks*32+grp*8)..+7
    short8 a[2];
    #pragma unroll
    for (int ks = 0; ks < 2; ++ks)
        a[ks] = *(const short8*)&lds[wv][row][(ks * 32 + grp * 8) ^ ((row & 7) << 3)];

    f32x4 acc[4];
    #pragma unroll
    for (int t = 0; t < 4; ++t) acc[t] = (f32x4){0.f, 0.f, 0.f, 0.f};
    #pragma unroll
    for (int t = 0; t < 4; ++t) {
        acc[t] = __builtin_amdgcn_mfma_f32_16x16x32_bf16(a[0], bfrag[t][0], acc[t], 0, 0, 0);
        acc[t] = __builtin_amdgcn_mfma_f32_16x16x32_bf16(a[1], bfrag[t][1], acc[t], 0, 0, 0);
    }

    // epilogue: C[m = grp*4+r][n = t*16+row]; store final rows
    #pragma unroll
    for (int r = 0; r < 4; ++r) {
        int vm = wl[e0 + grp * 4 + r];
        if (vm < 0) continue;
        unsigned short* op = grid + (size_t)vm * C_;
        #pragma unroll
        for (int t = 0; t < 4; ++t) {
            float val = fmaxf(acc[t][r] * sc[t] + sh[t], 0.f);
            op[t * 16 + row] = f2bf(val);
        }
    }
}

// ---------------- Stage 3: bilinear gather, 4 points per wave ----------------
__global__ __launch_bounds__(256) void k_gather4(
    const unsigned short* __restrict__ grid,
    const int* __restrict__ head,
    const float* __restrict__ vxyz,
    const float* __restrict__ g2, const float* __restrict__ b2,
    const float* __restrict__ m2, const float* __restrict__ v2,
    float* __restrict__ out)
{
    int lane = threadIdx.x & 63;
    int gw   = (blockIdx.x * 256 + threadIdx.x) >> 6;
    int p0   = gw * 4;
    if (p0 >= NPT_) return;

    float s2  = g2[lane] * rsqrtf(v2[lane] + 1e-3f);
    float cst = fmaxf(b2[lane] - m2[lane] * s2, 0.f);   // conv(0)+BN2+ReLU row

    #pragma unroll
    for (int k = 0; k < 4; ++k) {
        int pt = p0 + k;                      // NPT_ % 4 == 0
        int b  = pt / P_;
        float xq = vxyz[(size_t)pt * 3 + 0];
        float yq = vxyz[(size_t)pt * 3 + 1];
        int x0 = (int)floorf(xq); x0 = min(max(x0, 0), W_ - 1);
        int x1 = min(x0 + 1, W_ - 1);
        int y0 = (int)floorf(yq); y0 = min(max(y0, 0), H_ - 1);
        int y1 = min(y0 + 1, H_ - 1);
        float x0f = (float)x0, x1f = (float)x1, y0f = (float)y0, y1f = (float)y1;
        float wa = (x1f - xq) * (y1f - yq);
        float wb = (x1f - xq) * (yq - y0f);
        float wc = (xq - x0f) * (y1f - yq);
        float wd = (xq - x0f) * (yq - y0f);

        int ia = y0 * W_ + x0, ib = y1 * W_ + x0, ic = y0 * W_ + x1, id = y1 * W_ + x1;
        const int* hb = head + (size_t)b * S_;
        const unsigned short* g = grid + (size_t)b * S_ * C_;
        int ha = hb[ia], hbv = hb[ib], hc = hb[ic], hd = hb[id];
        float Ia = ha  >= 0 ? bf2f(g[(size_t)ia * C_ + lane]) : cst;
        float Ib = hbv >= 0 ? bf2f(g[(size_t)ib * C_ + lane]) : cst;
        float Ic = hc  >= 0 ? bf2f(g[(size_t)ic * C_ + lane]) : cst;
        float Id = hd  >= 0 ? bf2f(g[(size_t)id * C_ + lane]) : cst;

        out[(size_t)pt * C_ + lane] = wa * Ia + wb * Ib + wc * Ic + wd * Id;
    }
}

extern "C" void kernel_launch(void* const* d_in, const int* in_sizes, int n_in,
                              void* d_out, int out_size, void* d_ws, size_t ws_size,
                              hipStream_t stream)
{
    const float* feat     = (const float*)d_in[1];
    const int*   indices  = (const int*)d_in[3];
    const int*   paddings = (const int*)d_in[4];
    const float* vxyz     = (const float*)d_in[5];
    const float* w_pn     = (const float*)d_in[6];
    const float* g1       = (const float*)d_in[7];
    const float* b1       = (const float*)d_in[8];
    const float* m1       = (const float*)d_in[9];
    const float* v1       = (const float*)d_in[10];
    const float* cw       = (const float*)d_in[11];
    const float* g2       = (const float*)d_in[12];
    const float* b2       = (const float*)d_in[13];
    const float* m2       = (const float*)d_in[14];
    const float* v2       = (const float*)d_in[15];

    // ws layout: grid bf16 67.1MB | head 2.1MB | wl 0.8MB | next 0.8MB | cnt 4B
    unsigned short* grid = (unsigned short*)d_ws;
    char* base = (char*)d_ws + (size_t)NVOX_ * C_ * sizeof(unsigned short);
    int* head = (int*)base;
    int* wl   = head + NVOX_;
    int* next = wl + NPT_;
    int* cnt  = next + NPT_;

    hipMemsetAsync(head, 0xFF, (size_t)(NVOX_ + NPT_) * sizeof(int), stream); // head+wl=-1
    hipMemsetAsync(cnt, 0, sizeof(int), stream);

    k_fill<<<(NPT_ + 255) / 256, 256, 0, stream>>>(indices, paddings, head, next, wl, cnt);

    // ceil(NPT_/16)=12500 waves -> 3125 blocks (4 waves x 16 voxels = 64 entries/block)
    k_pn_conv<<<3125, 256, 0, stream>>>(
        feat, head, next, wl, w_pn, g1, b1, m1, v1, cw, g2, b2, m2, v2, grid);

    // 200000/4 = 50000 waves -> 12500 blocks
    k_gather4<<<12500, 256, 0, stream>>>(
        grid, head, vxyz, g2, b2, m2, v2, (float*)d_out);
}

// Round 7
// 123.581 us; speedup vs baseline: 2.1727x; 2.1727x over previous
//
#include <hip/hip_runtime.h>
#include <hip/hip_bf16.h>

#define B_ 2
#define P_ 100000
#define CIN_ 23
#define C_ 64
#define H_ 512
#define W_ 512
#define S_ (H_*W_)       // 262144
#define NPT_ (B_*P_)     // 200000
#define NVOX_ (B_*S_)    // 524288

typedef __attribute__((ext_vector_type(8))) short short8;
typedef __attribute__((ext_vector_type(4))) float f32x4;

__device__ inline unsigned short f2bf(float f) {
    union { __hip_bfloat16 h; unsigned short u; } cv;
    cv.h = __float2bfloat16(f);
    return cv.u;
}
__device__ inline float bf2f(unsigned short u) {
    union { unsigned int i; float f; } cv;
    cv.i = ((unsigned int)u) << 16;
    return cv.f;
}

// ---------------- Stage 1: build per-voxel linked lists ----------------
__global__ __launch_bounds__(256) void k_fill(
    const int* __restrict__ indices,
    const int* __restrict__ paddings,
    int* __restrict__ head,
    int* __restrict__ next)
{
    int pt = blockIdx.x * 256 + threadIdx.x;
    if (pt >= NPT_) return;
    if (paddings[pt] != 0) return;              // padded -> dropped
    int v = (pt / P_) * S_ + indices[pt];
    int old = atomicExch(&head[v], pt);
    next[pt] = old;
}

// ---------------- Stage 2: PointNet + max, DENSE, 4 voxels per wave ----------------
// lane = channel; 4 independent chain walks per wave; writes entire grid
// (zeros for empty voxels -> replaces memset; relu(-1e30*s+off)==0 exactly)
__global__ __launch_bounds__(256) void k_voxel4(
    const float* __restrict__ feat,
    const int* __restrict__ head,
    const int* __restrict__ next,
    const float* __restrict__ w_pn,
    const float* __restrict__ g1, const float* __restrict__ b1,
    const float* __restrict__ m1, const float* __restrict__ v1,
    unsigned short* __restrict__ grid)          // bf16 [NVOX_][C_]
{
    int lane = threadIdx.x & 63;
    int q    = (blockIdx.x * 256 + threadIdx.x) >> 6;   // quad id
    int v0   = q * 4;                                    // < NVOX_

    int pc[4];
    #pragma unroll
    for (int i = 0; i < 4; ++i)
        pc[i] = __builtin_amdgcn_readfirstlane(head[v0 + i]);

    // all-empty quad (~25%): write 512B of zeros, skip weight/param loads
    if (pc[0] < 0 && pc[1] < 0 && pc[2] < 0 && pc[3] < 0) {
        #pragma unroll
        for (int i = 0; i < 4; ++i)
            grid[(size_t)(v0 + i) * C_ + lane] = 0;
        return;
    }

    float w[CIN_];
    #pragma unroll
    for (int i = 0; i < CIN_; ++i) w[i] = w_pn[i * C_ + lane];

    float mx[4] = {-1e30f, -1e30f, -1e30f, -1e30f};

    while (pc[0] >= 0 || pc[1] >= 0 || pc[2] >= 0 || pc[3] >= 0) {
        #pragma unroll
        for (int i = 0; i < 4; ++i) {
            int p = pc[i];
            const float* f = feat + (size_t)(p < 0 ? 0 : p) * CIN_;
            int nx = p < 0 ? -1 : __builtin_amdgcn_readfirstlane(next[p]);
            float acc = 0.f;
            #pragma unroll
            for (int j = 0; j < CIN_; ++j) acc += f[j] * w[j];
            if (p >= 0) mx[i] = fmaxf(mx[i], acc);
            pc[i] = p < 0 ? -1 : nx;
        }
    }

    float s   = g1[lane] * rsqrtf(v1[lane] + 1e-5f);
    float off = b1[lane] - m1[lane] * s;
    #pragma unroll
    for (int i = 0; i < 4; ++i)
        grid[(size_t)(v0 + i) * C_ + lane] = f2bf(fmaxf(mx[i] * s + off, 0.f));
}

// ---------------- Stage 3: 1x1 conv (64x64) + BN2 + ReLU, in place, MFMA ----------------
// one wave per FOUR 16-voxel tiles (B-fragments + BN amortized 4x)
__global__ __launch_bounds__(256) void k_conv(
    unsigned short* __restrict__ grid,      // bf16
    const float* __restrict__ conv_w,       // [out n][in k] f32
    const float* __restrict__ g2, const float* __restrict__ b2,
    const float* __restrict__ m2, const float* __restrict__ v2)
{
    int lane = threadIdx.x & 63;
    int wv   = (blockIdx.x * 256 + threadIdx.x) >> 6;   // 0..8191
    int row  = lane & 15;       // A-row / B-col / C-col
    int grp  = lane >> 4;       // k-group

    // B fragments: lane holds B[k = ks*32 + grp*8 + j][n = t*16 + row] = W[n][k]
    short8 bfrag[4][2];
    #pragma unroll
    for (int t = 0; t < 4; ++t)
        #pragma unroll
        for (int ks = 0; ks < 2; ++ks) {
            const float* wp = conv_w + (t * 16 + row) * 64 + ks * 32 + grp * 8;
            f32x4 lo = *(const f32x4*)(wp);
            f32x4 hi = *(const f32x4*)(wp + 4);
            short8 vv;
            #pragma unroll
            for (int j = 0; j < 4; ++j) {
                vv[j]     = (short)f2bf(lo[j]);
                vv[j + 4] = (short)f2bf(hi[j]);
            }
            bfrag[t][ks] = vv;
        }

    float sc[4], sh[4];
    #pragma unroll
    for (int t = 0; t < 4; ++t) {
        int n   = t * 16 + row;
        float s = g2[n] * rsqrtf(v2[n] + 1e-3f);
        sc[t] = s;
        sh[t] = b2[n] - m2[n] * s;
    }

    #pragma unroll
    for (int sub = 0; sub < 4; ++sub) {
        unsigned short* gp = grid + ((size_t)wv * 4 + sub) * 16 * 64;

        short8 a[2];
        #pragma unroll
        for (int ks = 0; ks < 2; ++ks)
            a[ks] = *(const short8*)(gp + row * 64 + ks * 32 + grp * 8);

        f32x4 acc[4];
        #pragma unroll
        for (int t = 0; t < 4; ++t) acc[t] = (f32x4){0.f, 0.f, 0.f, 0.f};
        #pragma unroll
        for (int t = 0; t < 4; ++t) {
            acc[t] = __builtin_amdgcn_mfma_f32_16x16x32_bf16(a[0], bfrag[t][0], acc[t], 0, 0, 0);
            acc[t] = __builtin_amdgcn_mfma_f32_16x16x32_bf16(a[1], bfrag[t][1], acc[t], 0, 0, 0);
        }

        // epilogue: C[m = grp*4+r][n = t*16+row], BN2+ReLU, bf16 store in place
        #pragma unroll
        for (int t = 0; t < 4; ++t)
            #pragma unroll
            for (int r = 0; r < 4; ++r) {
                float val = fmaxf(acc[t][r] * sc[t] + sh[t], 0.f);
                gp[(grp * 4 + r) * 64 + t * 16 + row] = f2bf(val);
            }
    }
}

// ---------------- Stage 4: bilinear gather ----------------
// im[b,x,y] = v[b,y,x] -> voxel id = y*W + x ; one lane per (point, channel)
__global__ __launch_bounds__(256) void k_gather(
    const unsigned short* __restrict__ grid,   // bf16, dense final values
    const float* __restrict__ vxyz,
    float* __restrict__ out)                   // f32 output
{
    int t  = blockIdx.x * 256 + threadIdx.x;
    int c  = t & 63;
    int pt = t >> 6;
    if (pt >= NPT_) return;
    int b = pt / P_;

    float xq = vxyz[(size_t)pt * 3 + 0];
    float yq = vxyz[(size_t)pt * 3 + 1];
    int x0 = (int)floorf(xq); x0 = min(max(x0, 0), W_ - 1);
    int x1 = min(x0 + 1, W_ - 1);
    int y0 = (int)floorf(yq); y0 = min(max(y0, 0), H_ - 1);
    int y1 = min(y0 + 1, H_ - 1);
    float x0f = (float)x0, x1f = (float)x1, y0f = (float)y0, y1f = (float)y1;
    float wa = (x1f - xq) * (y1f - yq);
    float wb = (x1f - xq) * (yq - y0f);
    float wc = (xq - x0f) * (y1f - yq);
    float wd = (xq - x0f) * (yq - y0f);

    const unsigned short* g = grid + (size_t)b * S_ * C_;
    float Ia = bf2f(g[(size_t)(y0 * W_ + x0) * C_ + c]);
    float Ib = bf2f(g[(size_t)(y1 * W_ + x0) * C_ + c]);
    float Ic = bf2f(g[(size_t)(y0 * W_ + x1) * C_ + c]);
    float Id = bf2f(g[(size_t)(y1 * W_ + x1) * C_ + c]);

    out[t] = wa * Ia + wb * Ib + wc * Ic + wd * Id;
}

extern "C" void kernel_launch(void* const* d_in, const int* in_sizes, int n_in,
                              void* d_out, int out_size, void* d_ws, size_t ws_size,
                              hipStream_t stream)
{
    const float* feat     = (const float*)d_in[1];
    const int*   indices  = (const int*)d_in[3];
    const int*   paddings = (const int*)d_in[4];
    const float* vxyz     = (const float*)d_in[5];
    const float* w_pn     = (const float*)d_in[6];
    const float* g1       = (const float*)d_in[7];
    const float* b1       = (const float*)d_in[8];
    const float* m1       = (const float*)d_in[9];
    const float* v1       = (const float*)d_in[10];
    const float* cw       = (const float*)d_in[11];
    const float* g2       = (const float*)d_in[12];
    const float* b2       = (const float*)d_in[13];
    const float* m2       = (const float*)d_in[14];
    const float* v2       = (const float*)d_in[15];

    // ws layout: grid bf16 67.1MB | head 2.1MB | next 0.8MB
    unsigned short* grid = (unsigned short*)d_ws;
    int* head = (int*)((char*)d_ws + (size_t)NVOX_ * C_ * sizeof(unsigned short));
    int* next = head + NVOX_;

    hipMemsetAsync(head, 0xFF, (size_t)NVOX_ * sizeof(int), stream);   // head = -1

    k_fill<<<(NPT_ + 255) / 256, 256, 0, stream>>>(indices, paddings, head, next);

    // NVOX_/4 = 131072 waves -> 32768 blocks
    k_voxel4<<<32768, 256, 0, stream>>>(feat, head, next, w_pn, g1, b1, m1, v1, grid);

    // 8192 waves x 4 tiles -> 2048 blocks
    k_conv<<<2048, 256, 0, stream>>>(grid, cw, g2, b2, m2, v2);

    // 200000 waves -> 50000 blocks
    k_gather<<<50000, 256, 0, stream>>>(grid, vxyz, (float*)d_out);
}